// Round 15
// baseline (279.596 us; speedup 1.0000x reference)
//
#include <hip/hip_runtime.h>

typedef __bf16 bf16x8 __attribute__((ext_vector_type(8)));
typedef float  floatx4 __attribute__((ext_vector_type(4)));

constexpr int B_    = 2048;
constexpr int NIN   = 256;
constexpr int H_    = 128;
constexpr int RANK_ = 8;
constexpr float EPS_ = 1e-5f;

// ---------------------------------------------------------------------------
// HEAD: zero stats; lean in_proj (blocks 0..511, 4 rows each); pconv of ALL
// 8 ranks: upfront loads + bf16 OUTPUT-MAJOR LDS (scalar u16 scatter writes,
// vector b128 reads -> minimal LDS-pipe time). Grid 1024 x 256.
__global__ __launch_bounds__(256)
void k_head(const float* __restrict__ X,
            const float* __restrict__ W1, const float* __restrict__ b1,
            const float* __restrict__ W2, const float* __restrict__ b2,
            const float* __restrict__ P,
            float* __restrict__ R2, __bf16* __restrict__ Zbf,
            __bf16* __restrict__ Pperm, float* __restrict__ stats /* 9*256 */) {
    __shared__ float smem[4160];             // sx[1024] fp32 / sB[4096] bf16
    const int bx = blockIdx.x, t = threadIdx.x;

    if (bx < RANK_ + 1) stats[bx * 256 + t] = 0.f;

    if (bx < 512) {   // in_proj rows bx*4 .. +4; thread (col,rh) rows rh, rh+2
        const int b0 = bx * 4;
#pragma unroll
        for (int i = 0; i < 4; ++i) {
            const int e = i * 256 + t;
            smem[e] = X[(size_t)(b0 + (e >> 8)) * NIN + (e & 255)];
        }
        __syncthreads();
        const int col = t & 127, rh = t >> 7;
        float s1a = 0.f, s2a = 0.f, s1b = 0.f, s2b = 0.f;
        const float* sxa = smem + rh * 256;
        const float* sxb = smem + (rh + 2) * 256;
#pragma unroll 8
        for (int i = 0; i < NIN; ++i) {
            const float w1 = W1[i * H_ + col];
            const float w2 = W2[i * H_ + col];
            s1a = fmaf(sxa[i], w1, s1a);  s2a = fmaf(sxa[i], w2, s2a);
            s1b = fmaf(sxb[i], w1, s1b);  s2b = fmaf(sxb[i], w2, s2b);
        }
        const int ba = b0 + rh, bb = b0 + rh + 2;
        const float za = fmaxf(s1a + b1[col], 0.f), ra = fmaxf(s2a + b2[col], 0.f);
        const float zb = fmaxf(s1b + b1[col], 0.f), rb = fmaxf(s2b + b2[col], 0.f);
        Zbf[(size_t)ba * H_ + col] = (__bf16)za;  R2[(size_t)ba * H_ + col] = ra;
        Zbf[(size_t)bb * H_ + col] = (__bf16)zb;  R2[(size_t)bb * H_ + col] = rb;
        __syncthreads();
    }
    {   // pconv: unit = bx -> (rank r, p)
        const int r = bx >> 7, p = bx & 127;
        const float4* Pp4 = (const float4*)(P + ((size_t)r * H_ + p) * (H_ * H_));
        __bf16* dst = Pperm + (size_t)r * (H_ * H_ * H_);
        const int L = t & 63, g0 = t >> 6;
        __bf16* sB = (__bf16*)smem;          // 4096 bf16 = 8 KB per chunk

        float4 rg[4][4];                     // all 16 loads in flight at once
#pragma unroll
        for (int s = 0; s < 4; ++s)
#pragma unroll
            for (int it = 0; it < 4; ++it) {
                const int idx = it * 256 + t;
                rg[s][it] = Pp4[(size_t)(s * 32 + (idx >> 5)) * 32 + (idx & 31)];
            }
#pragma unroll
        for (int s = 0; s < 4; ++s) {
            if (s) __syncthreads();
            // scatter bf16 into output-major frag layout:
            // sB[g*512 + (quad*16+lo)*8 + j]  <-  val(q=quad*8+j, k=g*16+lo)
#pragma unroll
            for (int it = 0; it < 4; ++it) {
                const int idx = it * 256 + t;
                const int q = idx >> 5, k4 = idx & 31;
                const int qh = (q >> 3) * 128 + (q & 7);
                const int g  = k4 >> 2;
                const float4 v = rg[s][it];
                const float vv[4] = {v.x, v.y, v.z, v.w};
#pragma unroll
                for (int c = 0; c < 4; ++c) {
                    const int k = k4 * 4 + c;
                    sB[g * 512 + qh + (k & 15) * 8] = (__bf16)vv[c];
                }
            }
            __syncthreads();
#pragma unroll
            for (int gg = 0; gg < 2; ++gg) { // vector b128 reads, emit 16B
                const int g = g0 + 4 * gg;
                const bf16x8 v = *(const bf16x8*)&sB[g * 512 + L * 8];
                *(bf16x8*)(dst + (((size_t)(g * 128 + p) * 4 + s) * 64 + L) * 8) = v;
            }
        }
    }
}

// ---------------------------------------------------------------------------
// RANK r: T_r = sum_p BNprev(prev)[:,p] * (Zbf @ P_r[p]); stats_r.
// Grid (8 kg, 32 m) -> XCD = kg. 512 thr (8 waves), 2 blocks/CU.
// Wave w owns p in [w*16, w*16+16) x all 4 m-tiles; B read once per block.
__global__ __launch_bounds__(512, 2)
void k_rank(const __bf16* __restrict__ Pr, const __bf16* __restrict__ Zbf,
            const float* __restrict__ prevT, const float* __restrict__ prevStats,
            const float* __restrict__ gz, const float* __restrict__ bz,
            float* __restrict__ T, float* __restrict__ stats, const int first) {
    __shared__ float smem[8960];     // sZin[128][68] | reduce[8*1024]+cs; sAl/sBe tail
    const int kg = blockIdx.x, mblk = blockIdx.y, b0 = mblk * 64;
    const int t = threadIdx.x;
    const int w = t >> 6, L = t & 63, quad = L >> 4, lo = L & 15;

    float* sAl = smem + 8704; float* sBe = smem + 8832;
    if (!first && t < 128) {
        const float s1 = prevStats[t], s2 = prevStats[128 + t];
        const float mm = s1 * (1.f / B_);
        const float var = s2 * (1.f / B_) - mm * mm;
        const float a = rsqrtf(var + EPS_) * gz[t];
        sAl[t] = a; sBe[t] = bz[t] - mm * a;
    }
    // A-frags: 64 rows x K=128, rank-invariant (64 VGPRs)
    bf16x8 A[4][4];
#pragma unroll
    for (int mt = 0; mt < 4; ++mt)
#pragma unroll
        for (int ks = 0; ks < 4; ++ks)
            A[mt][ks] = *(const bf16x8*)(Zbf + (size_t)(b0 + mt * 16 + lo) * H_ + ks * 32 + quad * 8);
    __syncthreads();
    {   // stage zin -> sZin[p][row] (stride 68)
        const int sp = t & 127, rr = t >> 7;     // col, row-quarter
        if (first) {
#pragma unroll
            for (int i = 0; i < 16; ++i) {
                const int row = rr + 4 * i;
                smem[sp * 68 + row] = (float)Zbf[(size_t)(b0 + row) * H_ + sp];
            }
        } else {
            const float a = sAl[sp], be = sBe[sp];
#pragma unroll
            for (int i = 0; i < 16; ++i) {
                const int row = rr + 4 * i;
                smem[sp * 68 + row] = fmaf(prevT[(size_t)(b0 + row) * H_ + sp], a, be);
            }
        }
    }
    __syncthreads();

    floatx4 acc[4];
#pragma unroll
    for (int mt = 0; mt < 4; ++mt) acc[mt] = (floatx4){0.f, 0.f, 0.f, 0.f};

    const bf16x8* Pb = (const bf16x8*)Pr;
    const int p0 = w * 16;
    const size_t fbase = ((size_t)kg * 128 + p0) * 4;
    bf16x8 Bf[4], Bn[4];
#pragma unroll
    for (int s = 0; s < 4; ++s) Bf[s] = Pb[(fbase + s) * 64 + L];

    for (int pp = 0; pp < 16; ++pp) {
        const int p = p0 + pp;
        if (pp < 15) {
#pragma unroll
            for (int s = 0; s < 4; ++s)
                Bn[s] = Pb[(fbase + (size_t)(pp + 1) * 4 + s) * 64 + L];
        }
        floatx4 S[4];
#pragma unroll
        for (int mt = 0; mt < 4; ++mt) S[mt] = (floatx4){0.f, 0.f, 0.f, 0.f};
#pragma unroll
        for (int ks = 0; ks < 4; ++ks)
#pragma unroll
            for (int mt = 0; mt < 4; ++mt)
                S[mt] = __builtin_amdgcn_mfma_f32_16x16x32_bf16(A[mt][ks], Bf[ks], S[mt], 0, 0, 0);
#pragma unroll
        for (int mt = 0; mt < 4; ++mt) {
            const floatx4 zi = *(const floatx4*)&smem[p * 68 + mt * 16 + quad * 4];
            acc[mt] += zi * S[mt];
        }
#pragma unroll
        for (int s = 0; s < 4; ++s) Bf[s] = Bn[s];
    }
    __syncthreads();                 // sZin dead; reuse for cross-wave p-reduce
#pragma unroll
    for (int mt = 0; mt < 4; ++mt)
#pragma unroll
        for (int i = 0; i < 4; ++i)
            smem[w * 1024 + (mt * 4 + i) * 64 + L] = acc[mt][i];
    if (t < 32) smem[8192 + t] = 0.f;
    __syncthreads();

    float cs = 0.f, cs2 = 0.f;
#pragma unroll
    for (int k2 = 0; k2 < 2; ++k2) {
        const int e = t + 512 * k2;
        float v = 0.f;
#pragma unroll
        for (int q = 0; q < 8; ++q) v += smem[q * 1024 + e];
        const int j = e >> 6, L2 = e & 63;
        const int row = b0 + (j >> 2) * 16 + (L2 >> 4) * 4 + (j & 3);
        const int col = kg * 16 + (L2 & 15);
        T[(size_t)row * H_ + col] = v;
        cs += v; cs2 += v * v;
    }
    cs  += __shfl_xor(cs, 16);  cs  += __shfl_xor(cs, 32);
    cs2 += __shfl_xor(cs2, 16); cs2 += __shfl_xor(cs2, 32);
    if (L < 16) { atomicAdd(&smem[8192 + L], cs); atomicAdd(&smem[8208 + L], cs2); }
    __syncthreads();
    if (t < 16)      atomicAdd(&stats[kg * 16 + t],            smem[8192 + t]);
    else if (t < 32) atomicAdd(&stats[128 + kg * 16 + t - 16], smem[8192 + t]);
}

// ---------------------------------------------------------------------------
// Y = (1/8) sum_r BN_r(T_r); ystats. Grid 64 x 256.
__global__ __launch_bounds__(256)
void k_y(const float* __restrict__ T, const float* __restrict__ sums,
         const float* __restrict__ gz, const float* __restrict__ bz,
         float* __restrict__ Y, float* __restrict__ ysums) {
    __shared__ float al[1024], be[1024], red[256];
    const int bx = blockIdx.x, t = threadIdx.x;
    for (int e = t; e < 1024; e += 256) {
        const int rr = e >> 7, k = e & 127;
        const float s1 = sums[rr * 256 + k], s2 = sums[rr * 256 + 128 + k];
        const float mm = s1 * (1.f / B_);
        const float var = s2 * (1.f / B_) - mm * mm;
        const float a = rsqrtf(var + EPS_) * gz[k];
        al[e] = a; be[e] = bz[k] - mm * a;
    }
    red[t] = 0.f;
    __syncthreads();
    const int col = t & 127, half = t >> 7;
    float ps = 0.f, ps2 = 0.f;
    for (int i = 0; i < 16; ++i) {
        const int b = bx * 32 + half + 2 * i;
        float y = 0.f;
#pragma unroll
        for (int rr = 0; rr < 8; ++rr)
            y += fmaf(T[(size_t)rr * B_ * H_ + (size_t)b * H_ + col],
                      al[rr * 128 + col], be[rr * 128 + col]);
        y *= (1.f / RANK_);
        Y[(size_t)b * H_ + col] = y;
        ps += y; ps2 += y * y;
    }
    atomicAdd(&red[col],       half == 0 ? ps  : 0.f);
    atomicAdd(&red[128 + col], half == 0 ? ps2 : 0.f);
    __syncthreads();
    atomicAdd(&red[col],       half == 1 ? ps  : 0.f);
    atomicAdd(&red[128 + col], half == 1 ? ps2 : 0.f);
    __syncthreads();
    if (t < 128) {
        atomicAdd(&ysums[t],       red[t]);
        atomicAdd(&ysums[128 + t], red[128 + t]);
    }
}

// ---------------------------------------------------------------------------
// out = relu(relu(BN(Y)@W3 + b3) + R2). Grid 256 x 256, 8 rows per block.
__global__ __launch_bounds__(256)
void k_out(const float* __restrict__ Y, const float* __restrict__ ystats,
           const float* __restrict__ gy, const float* __restrict__ by,
           const float* __restrict__ W3, const float* __restrict__ b3,
           const float* __restrict__ R2, float* __restrict__ out) {
    __shared__ float sy[8 * 132];
    const int bx = blockIdx.x, t = threadIdx.x;
    const int col = t & 127, rh = t >> 7;
    const int b0 = bx * 8;
    const float mm = ystats[col] * (1.f / B_);
    const float var = ystats[128 + col] * (1.f / B_) - mm * mm;
    const float ay = rsqrtf(var + EPS_) * gy[col];
    const float bb = by[col] - mm * ay;
#pragma unroll
    for (int i = 0; i < 4; ++i) {
        const int row = rh + 2 * i;
        sy[row * 132 + col] = fmaf(Y[(size_t)(b0 + row) * H_ + col], ay, bb);
    }
    __syncthreads();
#pragma unroll
    for (int j = 0; j < 4; ++j) {
        const int row = rh * 4 + j;
        float s = 0.f;
        const float* syr = sy + row * 132;
#pragma unroll 8
        for (int h = 0; h < H_; ++h)
            s = fmaf(syr[h], W3[h * H_ + col], s);
        const size_t gi = (size_t)(b0 + row) * H_ + col;
        out[gi] = fmaxf(fmaxf(s + b3[col], 0.f) + R2[gi], 0.f);
    }
}

// ---------------------------------------------------------------------------
extern "C" void kernel_launch(void* const* d_in, const int* in_sizes, int n_in,
                              void* d_out, int out_size, void* d_ws, size_t ws_size,
                              hipStream_t stream) {
    const float* X  = (const float*)d_in[0];
    const float* W1 = (const float*)d_in[1];
    const float* b1 = (const float*)d_in[2];
    const float* W2 = (const float*)d_in[3];
    const float* b2 = (const float*)d_in[4];
    const float* W3 = (const float*)d_in[5];
    const float* b3 = (const float*)d_in[6];
    const float* P  = (const float*)d_in[7];
    const float* gz = (const float*)d_in[8];
    const float* bz = (const float*)d_in[9];
    const float* gy = (const float*)d_in[10];
    const float* by = (const float*)d_in[11];
    float* out = (float*)d_out;

    const size_t rankElems = (size_t)H_ * H_ * H_;

    char* wsb = (char*)d_ws;
    float* R2     = (float*)wsb;   wsb += (size_t)B_ * H_ * 4;
    float* Y      = (float*)wsb;   wsb += (size_t)B_ * H_ * 4;
    float* stats  = (float*)wsb;   wsb += (size_t)(RANK_ + 1) * 256 * 4;  // sums | ysums
    float* T      = (float*)wsb;   wsb += (size_t)RANK_ * B_ * H_ * 4;
    __bf16* Zbf   = (__bf16*)wsb;  wsb += (size_t)B_ * H_ * 2;
    __bf16* Pperm = (__bf16*)wsb;

    float* ysums = stats + RANK_ * 256;

    k_head<<<1024, 256, 0, stream>>>(X, W1, b1, W2, b2, P, R2, Zbf, Pperm, stats);

    for (int r = 0; r < RANK_; ++r) {
        const float* prevT = (r == 0) ? (const float*)Zbf : (T + (size_t)(r - 1) * B_ * H_);
        const float* prevS = (r == 0) ? stats : (stats + (r - 1) * 256);
        k_rank<<<dim3(8, 32), 512, 0, stream>>>(Pperm + (size_t)r * rankElems, Zbf,
                                                prevT, prevS, gz, bz,
                                                T + (size_t)r * B_ * H_, stats + r * 256,
                                                r == 0 ? 1 : 0);
    }

    k_y<<<64, 256, 0, stream>>>(T, stats, gz, bz, Y, ysums);
    k_out<<<256, 256, 0, stream>>>(Y, ysums, gy, by, W3, b3, R2, out);
}

// Round 16
// 273.248 us; speedup vs baseline: 1.0232x; 1.0232x over previous
//
#include <hip/hip_runtime.h>

typedef __bf16 bf16x8 __attribute__((ext_vector_type(8)));
typedef float  floatx4 __attribute__((ext_vector_type(4)));

constexpr int B_    = 2048;
constexpr int NIN   = 256;
constexpr int H_    = 128;
constexpr int RANK_ = 8;
constexpr float EPS_ = 1e-5f;

// ---------------------------------------------------------------------------
// HEAD: zero stats; JOB-SPLIT blocks: bx<512 -> in_proj (4 rows each);
// bx in [512,1536) -> one pconv unit (8 ranks x 128 p), upfront loads +
// fp32 stride-129 LDS transpose. Grid 1536 x 256.
__global__ __launch_bounds__(256)
void k_head(const float* __restrict__ X,
            const float* __restrict__ W1, const float* __restrict__ b1,
            const float* __restrict__ W2, const float* __restrict__ b2,
            const float* __restrict__ P,
            float* __restrict__ R2, __bf16* __restrict__ Zbf,
            __bf16* __restrict__ Pperm, float* __restrict__ stats /* 9*256 */) {
    __shared__ float smem[4160];             // sx[1024] / sT[32*129]
    const int bx = blockIdx.x, t = threadIdx.x;

    if (bx < RANK_ + 1) stats[bx * 256 + t] = 0.f;

    if (bx < 512) {   // in_proj rows bx*4 .. +4; thread (col,rh) rows rh, rh+2
        const int b0 = bx * 4;
#pragma unroll
        for (int i = 0; i < 4; ++i) {
            const int e = i * 256 + t;
            smem[e] = X[(size_t)(b0 + (e >> 8)) * NIN + (e & 255)];
        }
        __syncthreads();
        const int col = t & 127, rh = t >> 7;
        float s1a = 0.f, s2a = 0.f, s1b = 0.f, s2b = 0.f;
        const float* sxa = smem + rh * 256;
        const float* sxb = smem + (rh + 2) * 256;
#pragma unroll 8
        for (int i = 0; i < NIN; ++i) {
            const float w1 = W1[i * H_ + col];
            const float w2 = W2[i * H_ + col];
            s1a = fmaf(sxa[i], w1, s1a);  s2a = fmaf(sxa[i], w2, s2a);
            s1b = fmaf(sxb[i], w1, s1b);  s2b = fmaf(sxb[i], w2, s2b);
        }
        const int ba = b0 + rh, bb = b0 + rh + 2;
        const float za = fmaxf(s1a + b1[col], 0.f), ra = fmaxf(s2a + b2[col], 0.f);
        const float zb = fmaxf(s1b + b1[col], 0.f), rb = fmaxf(s2b + b2[col], 0.f);
        Zbf[(size_t)ba * H_ + col] = (__bf16)za;  R2[(size_t)ba * H_ + col] = ra;
        Zbf[(size_t)bb * H_ + col] = (__bf16)zb;  R2[(size_t)bb * H_ + col] = rb;
    } else {          // pconv: unit = bx-512 -> (rank r, p)
        const int u = bx - 512;
        const int r = u >> 7, p = u & 127;
        const float4* Pp4 = (const float4*)(P + ((size_t)r * H_ + p) * (H_ * H_));
        __bf16* dst = Pperm + (size_t)r * (H_ * H_ * H_);
        const int L = t & 63, quad = L >> 4, lo = L & 15, g0 = t >> 6;

        float4 rg[4][4];                     // all 16 loads in flight at once
#pragma unroll
        for (int s = 0; s < 4; ++s)
#pragma unroll
            for (int it = 0; it < 4; ++it) {
                const int idx = it * 256 + t;
                rg[s][it] = Pp4[(size_t)(s * 32 + (idx >> 5)) * 32 + (idx & 31)];
            }
#pragma unroll
        for (int s = 0; s < 4; ++s) {
            if (s) __syncthreads();
#pragma unroll
            for (int it = 0; it < 4; ++it) {
                const int idx = it * 256 + t;
                float* d = smem + (idx >> 5) * 129 + (idx & 31) * 4;
                d[0] = rg[s][it].x; d[1] = rg[s][it].y;
                d[2] = rg[s][it].z; d[3] = rg[s][it].w;
            }
            __syncthreads();
#pragma unroll
            for (int gg = 0; gg < 2; ++gg) {  // conflict-free reads, emit 16B
                const int g = g0 + 4 * gg;
                __bf16 v8[8];
#pragma unroll
                for (int j = 0; j < 8; ++j)
                    v8[j] = (__bf16)smem[(quad * 8 + j) * 129 + g * 16 + lo];
                *(bf16x8*)(dst + (((size_t)(g * 128 + p) * 4 + s) * 64 + L) * 8) =
                    *(const bf16x8*)v8;
            }
        }
    }
}

// ---------------------------------------------------------------------------
// RANK r: T_r = sum_p BNprev(prev)[:,p] * (Zbf @ P_r[p]); stats_r.
// Grid (8 kg, 32 m) -> XCD = kg. 512 thr (8 waves), 2 blocks/CU.
// Wave w owns p in [w*16, w*16+16) x all 4 m-tiles; B read once per block.
__global__ __launch_bounds__(512, 2)
void k_rank(const __bf16* __restrict__ Pr, const __bf16* __restrict__ Zbf,
            const float* __restrict__ prevT, const float* __restrict__ prevStats,
            const float* __restrict__ gz, const float* __restrict__ bz,
            float* __restrict__ T, float* __restrict__ stats, const int first) {
    __shared__ float smem[8960];     // sZin[128][68] | reduce[8*1024]+cs; sAl/sBe tail
    const int kg = blockIdx.x, mblk = blockIdx.y, b0 = mblk * 64;
    const int t = threadIdx.x;
    const int w = t >> 6, L = t & 63, quad = L >> 4, lo = L & 15;

    float* sAl = smem + 8704; float* sBe = smem + 8832;
    if (!first && t < 128) {
        const float s1 = prevStats[t], s2 = prevStats[128 + t];
        const float mm = s1 * (1.f / B_);
        const float var = s2 * (1.f / B_) - mm * mm;
        const float a = rsqrtf(var + EPS_) * gz[t];
        sAl[t] = a; sBe[t] = bz[t] - mm * a;
    }
    // A-frags: 64 rows x K=128, rank-invariant (64 VGPRs)
    bf16x8 A[4][4];
#pragma unroll
    for (int mt = 0; mt < 4; ++mt)
#pragma unroll
        for (int ks = 0; ks < 4; ++ks)
            A[mt][ks] = *(const bf16x8*)(Zbf + (size_t)(b0 + mt * 16 + lo) * H_ + ks * 32 + quad * 8);
    __syncthreads();
    {   // stage zin -> sZin[p][row] (stride 68)
        const int sp = t & 127, rr = t >> 7;     // col, row-quarter
        if (first) {
#pragma unroll
            for (int i = 0; i < 16; ++i) {
                const int row = rr + 4 * i;
                smem[sp * 68 + row] = (float)Zbf[(size_t)(b0 + row) * H_ + sp];
            }
        } else {
            const float a = sAl[sp], be = sBe[sp];
#pragma unroll
            for (int i = 0; i < 16; ++i) {
                const int row = rr + 4 * i;
                smem[sp * 68 + row] = fmaf(prevT[(size_t)(b0 + row) * H_ + sp], a, be);
            }
        }
    }
    __syncthreads();

    floatx4 acc[4];
#pragma unroll
    for (int mt = 0; mt < 4; ++mt) acc[mt] = (floatx4){0.f, 0.f, 0.f, 0.f};

    const bf16x8* Pb = (const bf16x8*)Pr;
    const int p0 = w * 16;
    const size_t fbase = ((size_t)kg * 128 + p0) * 4;
    bf16x8 Bf[4], Bn[4];
#pragma unroll
    for (int s = 0; s < 4; ++s) Bf[s] = Pb[(fbase + s) * 64 + L];

    for (int pp = 0; pp < 16; ++pp) {
        const int p = p0 + pp;
        if (pp < 15) {
#pragma unroll
            for (int s = 0; s < 4; ++s)
                Bn[s] = Pb[(fbase + (size_t)(pp + 1) * 4 + s) * 64 + L];
        }
        floatx4 S[4];
#pragma unroll
        for (int mt = 0; mt < 4; ++mt) S[mt] = (floatx4){0.f, 0.f, 0.f, 0.f};
#pragma unroll
        for (int ks = 0; ks < 4; ++ks)
#pragma unroll
            for (int mt = 0; mt < 4; ++mt)
                S[mt] = __builtin_amdgcn_mfma_f32_16x16x32_bf16(A[mt][ks], Bf[ks], S[mt], 0, 0, 0);
#pragma unroll
        for (int mt = 0; mt < 4; ++mt) {
            const floatx4 zi = *(const floatx4*)&smem[p * 68 + mt * 16 + quad * 4];
            acc[mt] += zi * S[mt];
        }
#pragma unroll
        for (int s = 0; s < 4; ++s) Bf[s] = Bn[s];
    }
    __syncthreads();                 // sZin dead; reuse for cross-wave p-reduce
#pragma unroll
    for (int mt = 0; mt < 4; ++mt)
#pragma unroll
        for (int i = 0; i < 4; ++i)
            smem[w * 1024 + (mt * 4 + i) * 64 + L] = acc[mt][i];
    if (t < 32) smem[8192 + t] = 0.f;
    __syncthreads();

    float cs = 0.f, cs2 = 0.f;
#pragma unroll
    for (int k2 = 0; k2 < 2; ++k2) {
        const int e = t + 512 * k2;
        float v = 0.f;
#pragma unroll
        for (int q = 0; q < 8; ++q) v += smem[q * 1024 + e];
        const int j = e >> 6, L2 = e & 63;
        const int row = b0 + (j >> 2) * 16 + (L2 >> 4) * 4 + (j & 3);
        const int col = kg * 16 + (L2 & 15);
        T[(size_t)row * H_ + col] = v;
        cs += v; cs2 += v * v;
    }
    cs  += __shfl_xor(cs, 16);  cs  += __shfl_xor(cs, 32);
    cs2 += __shfl_xor(cs2, 16); cs2 += __shfl_xor(cs2, 32);
    if (L < 16) { atomicAdd(&smem[8192 + L], cs); atomicAdd(&smem[8208 + L], cs2); }
    __syncthreads();
    if (t < 16)      atomicAdd(&stats[kg * 16 + t],            smem[8192 + t]);
    else if (t < 32) atomicAdd(&stats[128 + kg * 16 + t - 16], smem[8192 + t]);
}

// ---------------------------------------------------------------------------
// Y = (1/8) sum_r BN_r(T_r); ystats. Grid 64 x 256.
__global__ __launch_bounds__(256)
void k_y(const float* __restrict__ T, const float* __restrict__ sums,
         const float* __restrict__ gz, const float* __restrict__ bz,
         float* __restrict__ Y, float* __restrict__ ysums) {
    __shared__ float al[1024], be[1024], red[256];
    const int bx = blockIdx.x, t = threadIdx.x;
    for (int e = t; e < 1024; e += 256) {
        const int rr = e >> 7, k = e & 127;
        const float s1 = sums[rr * 256 + k], s2 = sums[rr * 256 + 128 + k];
        const float mm = s1 * (1.f / B_);
        const float var = s2 * (1.f / B_) - mm * mm;
        const float a = rsqrtf(var + EPS_) * gz[k];
        al[e] = a; be[e] = bz[k] - mm * a;
    }
    red[t] = 0.f;
    __syncthreads();
    const int col = t & 127, half = t >> 7;
    float ps = 0.f, ps2 = 0.f;
    for (int i = 0; i < 16; ++i) {
        const int b = bx * 32 + half + 2 * i;
        float y = 0.f;
#pragma unroll
        for (int rr = 0; rr < 8; ++rr)
            y += fmaf(T[(size_t)rr * B_ * H_ + (size_t)b * H_ + col],
                      al[rr * 128 + col], be[rr * 128 + col]);
        y *= (1.f / RANK_);
        Y[(size_t)b * H_ + col] = y;
        ps += y; ps2 += y * y;
    }
    atomicAdd(&red[col],       half == 0 ? ps  : 0.f);
    atomicAdd(&red[128 + col], half == 0 ? ps2 : 0.f);
    __syncthreads();
    atomicAdd(&red[col],       half == 1 ? ps  : 0.f);
    atomicAdd(&red[128 + col], half == 1 ? ps2 : 0.f);
    __syncthreads();
    if (t < 128) {
        atomicAdd(&ysums[t],       red[t]);
        atomicAdd(&ysums[128 + t], red[128 + t]);
    }
}

// ---------------------------------------------------------------------------
// out = relu(relu(BN(Y)@W3 + b3) + R2). Grid 256 x 256, 8 rows per block.
__global__ __launch_bounds__(256)
void k_out(const float* __restrict__ Y, const float* __restrict__ ystats,
           const float* __restrict__ gy, const float* __restrict__ by,
           const float* __restrict__ W3, const float* __restrict__ b3,
           const float* __restrict__ R2, float* __restrict__ out) {
    __shared__ float sy[8 * 132];
    const int bx = blockIdx.x, t = threadIdx.x;
    const int col = t & 127, rh = t >> 7;
    const int b0 = bx * 8;
    const float mm = ystats[col] * (1.f / B_);
    const float var = ystats[128 + col] * (1.f / B_) - mm * mm;
    const float ay = rsqrtf(var + EPS_) * gy[col];
    const float bb = by[col] - mm * ay;
#pragma unroll
    for (int i = 0; i < 4; ++i) {
        const int row = rh + 2 * i;
        sy[row * 132 + col] = fmaf(Y[(size_t)(b0 + row) * H_ + col], ay, bb);
    }
    __syncthreads();
#pragma unroll
    for (int j = 0; j < 4; ++j) {
        const int row = rh * 4 + j;
        float s = 0.f;
        const float* syr = sy + row * 132;
#pragma unroll 8
        for (int h = 0; h < H_; ++h)
            s = fmaf(syr[h], W3[h * H_ + col], s);
        const size_t gi = (size_t)(b0 + row) * H_ + col;
        out[gi] = fmaxf(fmaxf(s + b3[col], 0.f) + R2[gi], 0.f);
    }
}

// ---------------------------------------------------------------------------
extern "C" void kernel_launch(void* const* d_in, const int* in_sizes, int n_in,
                              void* d_out, int out_size, void* d_ws, size_t ws_size,
                              hipStream_t stream) {
    const float* X  = (const float*)d_in[0];
    const float* W1 = (const float*)d_in[1];
    const float* b1 = (const float*)d_in[2];
    const float* W2 = (const float*)d_in[3];
    const float* b2 = (const float*)d_in[4];
    const float* W3 = (const float*)d_in[5];
    const float* b3 = (const float*)d_in[6];
    const float* P  = (const float*)d_in[7];
    const float* gz = (const float*)d_in[8];
    const float* bz = (const float*)d_in[9];
    const float* gy = (const float*)d_in[10];
    const float* by = (const float*)d_in[11];
    float* out = (float*)d_out;

    const size_t rankElems = (size_t)H_ * H_ * H_;

    char* wsb = (char*)d_ws;
    float* R2     = (float*)wsb;   wsb += (size_t)B_ * H_ * 4;
    float* Y      = (float*)wsb;   wsb += (size_t)B_ * H_ * 4;
    float* stats  = (float*)wsb;   wsb += (size_t)(RANK_ + 1) * 256 * 4;  // sums | ysums
    float* T      = (float*)wsb;   wsb += (size_t)RANK_ * B_ * H_ * 4;
    __bf16* Zbf   = (__bf16*)wsb;  wsb += (size_t)B_ * H_ * 2;
    __bf16* Pperm = (__bf16*)wsb;

    float* ysums = stats + RANK_ * 256;

    k_head<<<1536, 256, 0, stream>>>(X, W1, b1, W2, b2, P, R2, Zbf, Pperm, stats);

    for (int r = 0; r < RANK_; ++r) {
        const float* prevT = (r == 0) ? (const float*)Zbf : (T + (size_t)(r - 1) * B_ * H_);
        const float* prevS = (r == 0) ? stats : (stats + (r - 1) * 256);
        k_rank<<<dim3(8, 32), 512, 0, stream>>>(Pperm + (size_t)r * rankElems, Zbf,
                                                prevT, prevS, gz, bz,
                                                T + (size_t)r * B_ * H_, stats + r * 256,
                                                r == 0 ? 1 : 0);
    }

    k_y<<<64, 256, 0, stream>>>(T, stats, gz, bz, Y, ysums);
    k_out<<<256, 256, 0, stream>>>(Y, ysums, gy, by, W3, b3, R2, out);
}